// Round 7
// baseline (158.080 us; speedup 1.0000x reference)
//
#include <hip/hip_runtime.h>
#include <hip/hip_bf16.h>
#include <hip/hip_fp8.h>
#include <math.h>

typedef __attribute__((ext_vector_type(4))) int   int4v;
typedef __attribute__((ext_vector_type(8))) int   int8v;
typedef __attribute__((ext_vector_type(4))) float f32x4;

#define AS1 __attribute__((address_space(1)))
#define AS3 __attribute__((address_space(3)))

// ---------------------------------------------------------------------------
// prep: grid-stride, one wave per row per iter. fp32 -> fp8 e4m3 (OCP) +
// exact fp32 ||row||^2. Also zeroes rowsum[M].
// ---------------------------------------------------------------------------
__global__ __launch_bounds__(256) void prep_kernel(
    const float* __restrict__ X, const float* __restrict__ S,
    unsigned char* __restrict__ Xq, unsigned char* __restrict__ Sq,
    float* __restrict__ x2, float* __restrict__ s2,
    float* __restrict__ rowsum, int M, int R, int Dv)
{
    const int gid  = blockIdx.x * 256 + threadIdx.x;
    const int nthr = gridDim.x * 256;

    for (int i = gid; i < M; i += nthr) rowsum[i] = 0.f;

    const int lane = threadIdx.x & 63;
    const int wid  = gid >> 6;
    const int nw   = nthr >> 6;

    for (int row = wid; row < R; row += nw) {
        const float* rp;
        unsigned char* op;
        float* sq;
        if (row < M) { rp = X + (size_t)row * Dv;       op = Xq + (size_t)row * Dv;       sq = x2 + row; }
        else         { rp = S + (size_t)(row - M) * Dv; op = Sq + (size_t)(row - M) * Dv; sq = s2 + (row - M); }

        float acc = 0.f;
        for (int k = lane * 8; k < Dv; k += 64 * 8) {
            float4 v0 = *(const float4*)(rp + k);
            float4 v1 = *(const float4*)(rp + k + 4);
            acc += v0.x * v0.x + v0.y * v0.y + v0.z * v0.z + v0.w * v0.w;
            acc += v1.x * v1.x + v1.y * v1.y + v1.z * v1.z + v1.w * v1.w;
            union { __hip_fp8_e4m3 h[8]; uint2 u; } pk;
            pk.h[0] = __hip_fp8_e4m3(v0.x);
            pk.h[1] = __hip_fp8_e4m3(v0.y);
            pk.h[2] = __hip_fp8_e4m3(v0.z);
            pk.h[3] = __hip_fp8_e4m3(v0.w);
            pk.h[4] = __hip_fp8_e4m3(v1.x);
            pk.h[5] = __hip_fp8_e4m3(v1.y);
            pk.h[6] = __hip_fp8_e4m3(v1.z);
            pk.h[7] = __hip_fp8_e4m3(v1.w);
            *(uint2*)(op + k) = pk.u;
        }
#pragma unroll
        for (int off = 1; off < 64; off <<= 1)
            acc += __shfl_xor(acc, off, 64);
        if (lane == 0) *sq = acc;
    }
}

// ---------------------------------------------------------------------------
// D=512 fused fp8 GEMM + exp-reduce, BARRIER-FREE K-sweep.
// Tile 64(m) x 256(n); 256 thr = 4 waves, wave w owns n-cols [w*64, w*64+64).
// A: all 64 rows x 512 B = 32 KB staged ONCE via global_load_lds
//    (16-B-chunk XOR swizzle phys = c ^ (row&7); linear-lane rule holds).
// B: loaded fragment-layout direct from global to registers, prefetched one
//    k-chunk (128 B) ahead. After the single __syncthreads there are NO
//    barriers: 64 MFMA + 32 ds_read_b128 + 32 global dwordx4 per wave,
//    latency covered by compiler vmcnt/lgkmcnt + 3 blocks/CU.
// ---------------------------------------------------------------------------
__global__ __launch_bounds__(256, 3) void kde_gemm512(
    const unsigned char* __restrict__ Xq,   // [M][512] fp8 e4m3
    const unsigned char* __restrict__ Sq,   // [N][512] fp8 e4m3
    const float* __restrict__ x2,
    const float* __restrict__ s2,
    const float* __restrict__ scale_p,
    float* __restrict__ rowsum,
    int M, int N)
{
    __shared__ char smem[32768];   // A tile; reused for epilogue reduction

    const int tid  = threadIdx.x;
    const int wave = tid >> 6;
    const int lane = tid & 63;
    const int quad = lane >> 4;
    const int l16  = lane & 15;

    const int m0 = blockIdx.x * 64;
    const int n0 = blockIdx.y * 256;
    const int wn = wave * 64;

    const float sc = *scale_p;

    // ---- A staging: 8 rounds x 4 KB (8 rows each). row&7 == t>>5 each round.
    const int srow = tid >> 5;                 // 0..7
    const int cg   = (tid & 31) ^ srow;        // global chunk for phys t&31
    const unsigned char* gA = Xq + (size_t)(m0 + srow) * 512 + cg * 16;
#pragma unroll
    for (int r = 0; r < 8; ++r)
        __builtin_amdgcn_global_load_lds(
            (const AS1 void*)(gA + (size_t)r * 8 * 512),
            (AS3 void*)(smem + r * 4096 + wave * 1024), 16, 0, 0);

    // ---- B prefetch for k-chunk c=0 (independent of the barrier)
    // fragment (ni,c): lane reads row n0+wn+ni*16+l16, bytes c*128+quad*32+{0,16}
    const unsigned char* gBf = Sq + (size_t)(n0 + wn + l16) * 512 + quad * 32;
    int4v blo[4], bhi[4];
#pragma unroll
    for (int ni = 0; ni < 4; ++ni) {
        blo[ni] = *(const int4v*)(gBf + (size_t)ni * 16 * 512);
        bhi[ni] = *(const int4v*)(gBf + (size_t)ni * 16 * 512 + 16);
    }

    f32x4 acc[4][4] = {};

    __syncthreads();   // the ONLY barrier before the epilogue (A staged)

    const int e = l16 & 7;
    const unsigned char* As = (const unsigned char*)smem;

#pragma unroll
    for (int c = 0; c < 4; ++c) {
        int8v bf[4];
#pragma unroll
        for (int ni = 0; ni < 4; ++ni)
            bf[ni] = (int8v){blo[ni].x, blo[ni].y, blo[ni].z, blo[ni].w,
                             bhi[ni].x, bhi[ni].y, bhi[ni].z, bhi[ni].w};
        if (c < 3) {   // prefetch next k-chunk
#pragma unroll
            for (int ni = 0; ni < 4; ++ni) {
                blo[ni] = *(const int4v*)(gBf + (size_t)ni * 16 * 512 + (c + 1) * 128);
                bhi[ni] = *(const int4v*)(gBf + (size_t)ni * 16 * 512 + (c + 1) * 128 + 16);
            }
        }
        int8v af[4];
#pragma unroll
        for (int mi = 0; mi < 4; ++mi) {
            // A row mi*16+l16, global chunks 8c+2q, 8c+2q+1; row&7 == e
            const unsigned char* rowp = As + (size_t)(mi * 16 + l16) * 512;
            int4v lo = *(const int4v*)(rowp + ((8 * c + 2 * quad)     ^ e) * 16);
            int4v hi = *(const int4v*)(rowp + ((8 * c + 2 * quad + 1) ^ e) * 16);
            af[mi] = (int8v){lo.x, lo.y, lo.z, lo.w, hi.x, hi.y, hi.z, hi.w};
        }
#pragma unroll
        for (int mi = 0; mi < 4; ++mi)
#pragma unroll
            for (int ni = 0; ni < 4; ++ni)
                acc[mi][ni] = __builtin_amdgcn_mfma_scale_f32_16x16x128_f8f6f4(
                    af[mi], bf[ni], acc[mi][ni],
                    0, 0, 0, 0x7F7F7F7F, 0, 0x7F7F7F7F);
    }

    // ---- epilogue. C layout: col = l16 (-> n), row = quad*4 + reg (-> m).
    __syncthreads();   // all waves done with As; reuse LDS
    float* wred = (float*)smem + wave * (64 * 20);  // 5120 B per wave

    float s2v[4];
#pragma unroll
    for (int ni = 0; ni < 4; ++ni)
        s2v[ni] = s2[n0 + wn + ni * 16 + l16];

#pragma unroll
    for (int mi = 0; mi < 4; ++mi) {
#pragma unroll
        for (int r = 0; r < 4; ++r) {
            const int rowL = mi * 16 + quad * 4 + r;   // 0..63
            const float xv = x2[m0 + rowL];
            float sum = 0.f;
#pragma unroll
            for (int ni = 0; ni < 4; ++ni) {
                float d2 = xv + s2v[ni] - 2.0f * acc[mi][ni][r];
                d2 = fmaxf(d2, 0.f);
                sum += __expf(-sc * d2);
            }
            wred[rowL * 20 + l16] = sum;
        }
    }
    __syncthreads();

    // each wave reduces its own 64-row strip; 4 atomics per output row/block
    float* rp = wred + lane * 20;
    float4 p0 = *(float4*)(rp + 0);
    float4 p1 = *(float4*)(rp + 4);
    float4 p2 = *(float4*)(rp + 8);
    float4 p3 = *(float4*)(rp + 12);
    float s = (p0.x + p0.y + p0.z + p0.w) + (p1.x + p1.y + p1.z + p1.w)
            + (p2.x + p2.y + p2.z + p2.w) + (p3.x + p3.y + p3.z + p3.w);
    atomicAdd(&rowsum[m0 + lane], s);
}

// ---------------------------------------------------------------------------
// Generic-D fallback (R4 structure, verified): 2-barrier K-loop, BK=128.
// ---------------------------------------------------------------------------
__global__ __launch_bounds__(256, 3) void kde_gemm_generic(
    const unsigned char* __restrict__ Xq, const unsigned char* __restrict__ Sq,
    const float* __restrict__ x2, const float* __restrict__ s2,
    const float* __restrict__ scale_p, float* __restrict__ rowsum,
    int M, int N, int Dv)
{
    const int D = Dv;
    __shared__ char smem[32768];
    unsigned char* As = (unsigned char*)smem;
    unsigned char* Bs = (unsigned char*)(smem + 16384);

    const int tid  = threadIdx.x;
    const int wave = tid >> 6;
    const int lane = tid & 63;
    const int quad = lane >> 4;
    const int l16  = lane & 15;

    const int m0 = blockIdx.x * 128;
    const int n0 = blockIdx.y * 128;
    const int wm = (wave & 1) * 64;
    const int wn = (wave >> 1) * 64;

    const float sc = *scale_p;
    f32x4 acc[4][4] = {};

    const int srow0 = wave * 8 + (lane >> 3);
    const int cg    = (lane & 7) ^ (lane >> 3);
    const unsigned char* gA = Xq + (size_t)(m0 + srow0) * D + cg * 16;
    const unsigned char* gB = Sq + (size_t)(n0 + srow0) * D + cg * 16;

    for (int k0 = 0; k0 < D; k0 += 128) {
        __syncthreads();
#pragma unroll
        for (int rd = 0; rd < 4; ++rd)
            __builtin_amdgcn_global_load_lds(
                (const AS1 void*)(gA + (size_t)rd * 32 * D + k0),
                (AS3 void*)(smem + rd * 4096 + wave * 1024), 16, 0, 0);
#pragma unroll
        for (int rd = 0; rd < 4; ++rd)
            __builtin_amdgcn_global_load_lds(
                (const AS1 void*)(gB + (size_t)rd * 32 * D + k0),
                (AS3 void*)(smem + 16384 + rd * 4096 + wave * 1024), 16, 0, 0);
        __syncthreads();

        const int e = l16 & 7;
        int8v a_frag[4], b_frag[4];
#pragma unroll
        for (int mi = 0; mi < 4; ++mi) {
            const unsigned char* rowp = As + (wm + mi * 16 + l16) * 128;
            int4v lo = *(const int4v*)(rowp + ((2 * quad)     ^ e) * 16);
            int4v hi = *(const int4v*)(rowp + ((2 * quad + 1) ^ e) * 16);
            a_frag[mi] = (int8v){lo.x, lo.y, lo.z, lo.w, hi.x, hi.y, hi.z, hi.w};
        }
#pragma unroll
        for (int ni = 0; ni < 4; ++ni) {
            const unsigned char* rowp = Bs + (wn + ni * 16 + l16) * 128;
            int4v lo = *(const int4v*)(rowp + ((2 * quad)     ^ e) * 16);
            int4v hi = *(const int4v*)(rowp + ((2 * quad + 1) ^ e) * 16);
            b_frag[ni] = (int8v){lo.x, lo.y, lo.z, lo.w, hi.x, hi.y, hi.z, hi.w};
        }
#pragma unroll
        for (int mi = 0; mi < 4; ++mi)
#pragma unroll
            for (int ni = 0; ni < 4; ++ni)
                acc[mi][ni] = __builtin_amdgcn_mfma_scale_f32_16x16x128_f8f6f4(
                    a_frag[mi], b_frag[ni], acc[mi][ni],
                    0, 0, 0, 0x7F7F7F7F, 0, 0x7F7F7F7F);
    }

    __syncthreads();
    float* wred = (float*)smem + wave * (64 * 20);

    float s2v[4];
#pragma unroll
    for (int ni = 0; ni < 4; ++ni)
        s2v[ni] = s2[n0 + wn + ni * 16 + l16];

#pragma unroll
    for (int mi = 0; mi < 4; ++mi) {
#pragma unroll
        for (int r = 0; r < 4; ++r) {
            const int rowL = mi * 16 + quad * 4 + r;
            const float xv = x2[m0 + wm + rowL];
            float sum = 0.f;
#pragma unroll
            for (int ni = 0; ni < 4; ++ni) {
                float d2 = xv + s2v[ni] - 2.0f * acc[mi][ni][r];
                d2 = fmaxf(d2, 0.f);
                sum += __expf(-sc * d2);
            }
            wred[rowL * 20 + l16] = sum;
        }
    }
    __syncthreads();

    float4 p0 = *(float4*)(wred + lane * 20 + 0);
    float4 p1 = *(float4*)(wred + lane * 20 + 4);
    float4 p2 = *(float4*)(wred + lane * 20 + 8);
    float4 p3 = *(float4*)(wred + lane * 20 + 12);
    float s = (p0.x + p0.y + p0.z + p0.w) + (p1.x + p1.y + p1.z + p1.w)
            + (p2.x + p2.y + p2.z + p2.w) + (p3.x + p3.y + p3.z + p3.w);
    atomicAdd(&rowsum[m0 + wm + lane], s);
}

// ---------------------------------------------------------------------------
__global__ void finalize_kernel(const float* __restrict__ rowsum,
                                const float* __restrict__ scale_p,
                                float* __restrict__ out, int M, int N, int Dv) {
    const int m = blockIdx.x * 256 + threadIdx.x;
    if (m < M) {
        const float sc = *scale_p;
        const float cst = -logf((float)N) + 0.5f * (float)Dv * logf(sc / 3.14159265358979f);
        out[m] = logf(rowsum[m]) + cst;
    }
}

// ---------------------------------------------------------------------------
extern "C" void kernel_launch(void* const* d_in, const int* in_sizes, int n_in,
                              void* d_out, int out_size, void* d_ws, size_t ws_size,
                              hipStream_t stream) {
    const float* X       = (const float*)d_in[0];
    const float* S       = (const float*)d_in[1];
    const float* scale_p = (const float*)d_in[2];
    float* out = (float*)d_out;

    const int M  = out_size;            // 8192
    const int Dv = in_sizes[0] / M;     // 512
    const int N  = in_sizes[1] / Dv;    // 8192

    char* ws = (char*)d_ws;
    unsigned char* Xq = (unsigned char*)ws;
    unsigned char* Sq = (unsigned char*)(ws + (size_t)M * Dv);
    float* x2     = (float*)(ws + (size_t)M * Dv + (size_t)N * Dv);
    float* s2     = x2 + M;
    float* rowsum = s2 + N;

    prep_kernel<<<512, 256, 0, stream>>>(X, S, Xq, Sq, x2, s2, rowsum, M, M + N, Dv);

    if (Dv == 512) {
        dim3 grid(M / 64, N / 256);
        kde_gemm512<<<grid, 256, 0, stream>>>(Xq, Sq, x2, s2, scale_p, rowsum, M, N);
    } else {
        dim3 grid(M / 128, N / 128);
        kde_gemm_generic<<<grid, 256, 0, stream>>>(Xq, Sq, x2, s2, scale_p, rowsum, M, N, Dv);
    }

    finalize_kernel<<<(M + 255) / 256, 256, 0, stream>>>(rowsum, scale_p, out, M, N, Dv);
}

// Round 8
// 149.597 us; speedup vs baseline: 1.0567x; 1.0567x over previous
//
#include <hip/hip_runtime.h>
#include <hip/hip_bf16.h>
#include <hip/hip_fp8.h>
#include <math.h>

typedef __attribute__((ext_vector_type(4))) int   int4v;
typedef __attribute__((ext_vector_type(8))) int   int8v;
typedef __attribute__((ext_vector_type(4))) float f32x4;

#define AS1 __attribute__((address_space(1)))
#define AS3 __attribute__((address_space(3)))

// ---------------------------------------------------------------------------
// prep: grid-stride, one wave per row per iter. fp32 -> fp8 e4m3 (OCP) +
// exact fp32 ||row||^2. Also zeroes rowsum[M].
// ---------------------------------------------------------------------------
__global__ __launch_bounds__(256) void prep_kernel(
    const float* __restrict__ X, const float* __restrict__ S,
    unsigned char* __restrict__ Xq, unsigned char* __restrict__ Sq,
    float* __restrict__ x2, float* __restrict__ s2,
    float* __restrict__ rowsum, int M, int R, int Dv)
{
    const int gid  = blockIdx.x * 256 + threadIdx.x;
    const int nthr = gridDim.x * 256;

    for (int i = gid; i < M; i += nthr) rowsum[i] = 0.f;

    const int lane = threadIdx.x & 63;
    const int wid  = gid >> 6;
    const int nw   = nthr >> 6;

    for (int row = wid; row < R; row += nw) {
        const float* rp;
        unsigned char* op;
        float* sq;
        if (row < M) { rp = X + (size_t)row * Dv;       op = Xq + (size_t)row * Dv;       sq = x2 + row; }
        else         { rp = S + (size_t)(row - M) * Dv; op = Sq + (size_t)(row - M) * Dv; sq = s2 + (row - M); }

        float acc = 0.f;
        for (int k = lane * 8; k < Dv; k += 64 * 8) {
            float4 v0 = *(const float4*)(rp + k);
            float4 v1 = *(const float4*)(rp + k + 4);
            acc += v0.x * v0.x + v0.y * v0.y + v0.z * v0.z + v0.w * v0.w;
            acc += v1.x * v1.x + v1.y * v1.y + v1.z * v1.z + v1.w * v1.w;
            union { __hip_fp8_e4m3 h[8]; uint2 u; } pk;
            pk.h[0] = __hip_fp8_e4m3(v0.x);
            pk.h[1] = __hip_fp8_e4m3(v0.y);
            pk.h[2] = __hip_fp8_e4m3(v0.z);
            pk.h[3] = __hip_fp8_e4m3(v0.w);
            pk.h[4] = __hip_fp8_e4m3(v1.x);
            pk.h[5] = __hip_fp8_e4m3(v1.y);
            pk.h[6] = __hip_fp8_e4m3(v1.z);
            pk.h[7] = __hip_fp8_e4m3(v1.w);
            *(uint2*)(op + k) = pk.u;
        }
#pragma unroll
        for (int off = 1; off < 64; off <<= 1)
            acc += __shfl_xor(acc, off, 64);
        if (lane == 0) *sq = acc;
    }
}

// ---------------------------------------------------------------------------
// D=512 fused fp8 GEMM + exp-reduce. R4 2-barrier skeleton, widened:
// 512 threads = 8 waves (4m x 2n grid of 64x64 quadrants), tile 256x128,
// BK=128, single 48 KB buffer (A 32 KB + B 16 KB), 4 K-iters.
// L2 traffic per output drops 25% vs 128x128; MFMA work per CU-gen +33%.
// LDS 16-B-chunk XOR swizzle phys = c ^ (row&7) (R2/R4-verified).
// ---------------------------------------------------------------------------
__global__ __launch_bounds__(512, 4) void kde_gemm512(
    const unsigned char* __restrict__ Xq,   // [M][512] fp8 e4m3
    const unsigned char* __restrict__ Sq,   // [N][512] fp8 e4m3
    const float* __restrict__ x2,
    const float* __restrict__ s2,
    const float* __restrict__ scale_p,
    float* __restrict__ rowsum,
    int M, int N)
{
    __shared__ char smem[49152];   // As [256][128] 32 KB | Bs [128][128] 16 KB
    unsigned char* As = (unsigned char*)smem;
    unsigned char* Bs = (unsigned char*)(smem + 32768);

    const int tid  = threadIdx.x;
    const int wave = tid >> 6;
    const int lane = tid & 63;
    const int quad = lane >> 4;
    const int l16  = lane & 15;

    const int m0 = blockIdx.x * 256;
    const int n0 = blockIdx.y * 128;
    const int wm = (wave >> 1) * 64;   // 4 m-strips
    const int wn = (wave & 1) * 64;    // 2 n-strips

    const float sc = *scale_p;

    f32x4 acc[4][4] = {};

    // staging map: a round covers 64 rows x 128 B = 8 KB (512 thr x 16 B).
    // thread t: row-in-round = t>>3, phys chunk = t&7,
    // global chunk = (t&7) ^ (row&7) = (t&7) ^ ((t>>3)&7).
    // LDS dst = round_base + t*16  (wave-uniform base + lane*16  ✓).
    const int srow = tid >> 3;                     // 0..63
    const int cg   = (tid & 7) ^ (srow & 7);
    const unsigned char* gA = Xq + (size_t)(m0 + srow) * 512 + cg * 16;
    const unsigned char* gB = Sq + (size_t)(n0 + srow) * 512 + cg * 16;

#pragma unroll
    for (int k0 = 0; k0 < 512; k0 += 128) {
        __syncthreads();  // prev iter's ds_reads done before overwrite
#pragma unroll
        for (int rd = 0; rd < 4; ++rd)   // A: 4 rounds of 64 rows
            __builtin_amdgcn_global_load_lds(
                (const AS1 void*)(gA + (size_t)rd * 64 * 512 + k0),
                (AS3 void*)(smem + rd * 8192 + wave * 1024), 16, 0, 0);
#pragma unroll
        for (int rd = 0; rd < 2; ++rd)   // B: 2 rounds of 64 rows
            __builtin_amdgcn_global_load_lds(
                (const AS1 void*)(gB + (size_t)rd * 64 * 512 + k0),
                (AS3 void*)(smem + 32768 + rd * 8192 + wave * 1024), 16, 0, 0);
        __syncthreads();  // staging drained

        const int e = l16 & 7;
        int8v a_frag[4], b_frag[4];
#pragma unroll
        for (int mi = 0; mi < 4; ++mi) {
            const unsigned char* rowp = As + (size_t)(wm + mi * 16 + l16) * 128;
            int4v lo = *(const int4v*)(rowp + ((2 * quad)     ^ e) * 16);
            int4v hi = *(const int4v*)(rowp + ((2 * quad + 1) ^ e) * 16);
            a_frag[mi] = (int8v){lo.x, lo.y, lo.z, lo.w, hi.x, hi.y, hi.z, hi.w};
        }
#pragma unroll
        for (int ni = 0; ni < 4; ++ni) {
            const unsigned char* rowp = Bs + (size_t)(wn + ni * 16 + l16) * 128;
            int4v lo = *(const int4v*)(rowp + ((2 * quad)     ^ e) * 16);
            int4v hi = *(const int4v*)(rowp + ((2 * quad + 1) ^ e) * 16);
            b_frag[ni] = (int8v){lo.x, lo.y, lo.z, lo.w, hi.x, hi.y, hi.z, hi.w};
        }
#pragma unroll
        for (int mi = 0; mi < 4; ++mi)
#pragma unroll
            for (int ni = 0; ni < 4; ++ni)
                acc[mi][ni] = __builtin_amdgcn_mfma_scale_f32_16x16x128_f8f6f4(
                    a_frag[mi], b_frag[ni], acc[mi][ni],
                    0, 0, 0, 0x7F7F7F7F, 0, 0x7F7F7F7F);
    }

    // ---- epilogue. C layout: col = l16 (-> n), row = quad*4 + reg (-> m).
    __syncthreads();  // all waves done reading As/Bs; reuse LDS
    float* wred = (float*)(smem + wave * 5120);   // 8 x 5120 B = 40 KB

    float s2v[4];
#pragma unroll
    for (int ni = 0; ni < 4; ++ni)
        s2v[ni] = s2[n0 + wn + ni * 16 + l16];

#pragma unroll
    for (int mi = 0; mi < 4; ++mi) {
#pragma unroll
        for (int r = 0; r < 4; ++r) {
            const int rowL = mi * 16 + quad * 4 + r;   // 0..63 within wave
            const float xv = x2[m0 + wm + rowL];
            float sum = 0.f;
#pragma unroll
            for (int ni = 0; ni < 4; ++ni) {
                float d2 = xv + s2v[ni] - 2.0f * acc[mi][ni][r];
                d2 = fmaxf(d2, 0.f);
                sum += __expf(-sc * d2);
            }
            wred[rowL * 20 + l16] = sum;
        }
    }
    __syncthreads();

    float* rp = wred + lane * 20;
    float4 p0 = *(float4*)(rp + 0);
    float4 p1 = *(float4*)(rp + 4);
    float4 p2 = *(float4*)(rp + 8);
    float4 p3 = *(float4*)(rp + 12);
    float s = (p0.x + p0.y + p0.z + p0.w) + (p1.x + p1.y + p1.z + p1.w)
            + (p2.x + p2.y + p2.z + p2.w) + (p3.x + p3.y + p3.z + p3.w);
    atomicAdd(&rowsum[m0 + wm + lane], s);
}

// ---------------------------------------------------------------------------
// Generic-D fallback (R4 structure, verified): 2-barrier K-loop, BK=128.
// ---------------------------------------------------------------------------
__global__ __launch_bounds__(256, 3) void kde_gemm_generic(
    const unsigned char* __restrict__ Xq, const unsigned char* __restrict__ Sq,
    const float* __restrict__ x2, const float* __restrict__ s2,
    const float* __restrict__ scale_p, float* __restrict__ rowsum,
    int M, int N, int Dv)
{
    const int D = Dv;
    __shared__ char smem[32768];
    unsigned char* As = (unsigned char*)smem;
    unsigned char* Bs = (unsigned char*)(smem + 16384);

    const int tid  = threadIdx.x;
    const int wave = tid >> 6;
    const int lane = tid & 63;
    const int quad = lane >> 4;
    const int l16  = lane & 15;

    const int m0 = blockIdx.x * 128;
    const int n0 = blockIdx.y * 128;
    const int wm = (wave & 1) * 64;
    const int wn = (wave >> 1) * 64;

    const float sc = *scale_p;
    f32x4 acc[4][4] = {};

    const int srow0 = wave * 8 + (lane >> 3);
    const int cg    = (lane & 7) ^ (lane >> 3);
    const unsigned char* gA = Xq + (size_t)(m0 + srow0) * D + cg * 16;
    const unsigned char* gB = Sq + (size_t)(n0 + srow0) * D + cg * 16;

    for (int k0 = 0; k0 < D; k0 += 128) {
        __syncthreads();
#pragma unroll
        for (int rd = 0; rd < 4; ++rd)
            __builtin_amdgcn_global_load_lds(
                (const AS1 void*)(gA + (size_t)rd * 32 * D + k0),
                (AS3 void*)(smem + rd * 4096 + wave * 1024), 16, 0, 0);
#pragma unroll
        for (int rd = 0; rd < 4; ++rd)
            __builtin_amdgcn_global_load_lds(
                (const AS1 void*)(gB + (size_t)rd * 32 * D + k0),
                (AS3 void*)(smem + 16384 + rd * 4096 + wave * 1024), 16, 0, 0);
        __syncthreads();

        const int e = l16 & 7;
        int8v a_frag[4], b_frag[4];
#pragma unroll
        for (int mi = 0; mi < 4; ++mi) {
            const unsigned char* rowp = As + (wm + mi * 16 + l16) * 128;
            int4v lo = *(const int4v*)(rowp + ((2 * quad)     ^ e) * 16);
            int4v hi = *(const int4v*)(rowp + ((2 * quad + 1) ^ e) * 16);
            a_frag[mi] = (int8v){lo.x, lo.y, lo.z, lo.w, hi.x, hi.y, hi.z, hi.w};
        }
#pragma unroll
        for (int ni = 0; ni < 4; ++ni) {
            const unsigned char* rowp = Bs + (wn + ni * 16 + l16) * 128;
            int4v lo = *(const int4v*)(rowp + ((2 * quad)     ^ e) * 16);
            int4v hi = *(const int4v*)(rowp + ((2 * quad + 1) ^ e) * 16);
            b_frag[ni] = (int8v){lo.x, lo.y, lo.z, lo.w, hi.x, hi.y, hi.z, hi.w};
        }
#pragma unroll
        for (int mi = 0; mi < 4; ++mi)
#pragma unroll
            for (int ni = 0; ni < 4; ++ni)
                acc[mi][ni] = __builtin_amdgcn_mfma_scale_f32_16x16x128_f8f6f4(
                    a_frag[mi], b_frag[ni], acc[mi][ni],
                    0, 0, 0, 0x7F7F7F7F, 0, 0x7F7F7F7F);
    }

    __syncthreads();
    float* wred = (float*)smem + wave * (64 * 20);

    float s2v[4];
#pragma unroll
    for (int ni = 0; ni < 4; ++ni)
        s2v[ni] = s2[n0 + wn + ni * 16 + l16];

#pragma unroll
    for (int mi = 0; mi < 4; ++mi) {
#pragma unroll
        for (int r = 0; r < 4; ++r) {
            const int rowL = mi * 16 + quad * 4 + r;
            const float xv = x2[m0 + wm + rowL];
            float sum = 0.f;
#pragma unroll
            for (int ni = 0; ni < 4; ++ni) {
                float d2 = xv + s2v[ni] - 2.0f * acc[mi][ni][r];
                d2 = fmaxf(d2, 0.f);
                sum += __expf(-sc * d2);
            }
            wred[rowL * 20 + l16] = sum;
        }
    }
    __syncthreads();

    float4 p0 = *(float4*)(wred + lane * 20 + 0);
    float4 p1 = *(float4*)(wred + lane * 20 + 4);
    float4 p2 = *(float4*)(wred + lane * 20 + 8);
    float4 p3 = *(float4*)(wred + lane * 20 + 12);
    float s = (p0.x + p0.y + p0.z + p0.w) + (p1.x + p1.y + p1.z + p1.w)
            + (p2.x + p2.y + p2.z + p2.w) + (p3.x + p3.y + p3.z + p3.w);
    atomicAdd(&rowsum[m0 + wm + lane], s);
}

// ---------------------------------------------------------------------------
__global__ void finalize_kernel(const float* __restrict__ rowsum,
                                const float* __restrict__ scale_p,
                                float* __restrict__ out, int M, int N, int Dv) {
    const int m = blockIdx.x * 256 + threadIdx.x;
    if (m < M) {
        const float sc = *scale_p;
        const float cst = -logf((float)N) + 0.5f * (float)Dv * logf(sc / 3.14159265358979f);
        out[m] = logf(rowsum[m]) + cst;
    }
}

// ---------------------------------------------------------------------------
extern "C" void kernel_launch(void* const* d_in, const int* in_sizes, int n_in,
                              void* d_out, int out_size, void* d_ws, size_t ws_size,
                              hipStream_t stream) {
    const float* X       = (const float*)d_in[0];
    const float* S       = (const float*)d_in[1];
    const float* scale_p = (const float*)d_in[2];
    float* out = (float*)d_out;

    const int M  = out_size;            // 8192
    const int Dv = in_sizes[0] / M;     // 512
    const int N  = in_sizes[1] / Dv;    // 8192

    char* ws = (char*)d_ws;
    unsigned char* Xq = (unsigned char*)ws;
    unsigned char* Sq = (unsigned char*)(ws + (size_t)M * Dv);
    float* x2     = (float*)(ws + (size_t)M * Dv + (size_t)N * Dv);
    float* s2     = x2 + M;
    float* rowsum = s2 + N;

    prep_kernel<<<512, 256, 0, stream>>>(X, S, Xq, Sq, x2, s2, rowsum, M, M + N, Dv);

    if (Dv == 512 && (M % 256) == 0 && (N % 128) == 0) {
        dim3 grid(M / 256, N / 128);
        kde_gemm512<<<grid, 512, 0, stream>>>(Xq, Sq, x2, s2, scale_p, rowsum, M, N);
    } else {
        dim3 grid(M / 128, N / 128);
        kde_gemm_generic<<<grid, 256, 0, stream>>>(Xq, Sq, x2, s2, scale_p, rowsum, M, N, Dv);
    }

    finalize_kernel<<<(M + 255) / 256, 256, 0, stream>>>(rowsum, scale_p, out, M, N, Dv);
}

// Round 9
// 144.233 us; speedup vs baseline: 1.0960x; 1.0372x over previous
//
#include <hip/hip_runtime.h>
#include <hip/hip_bf16.h>
#include <hip/hip_fp8.h>
#include <math.h>

typedef __attribute__((ext_vector_type(4))) int   int4v;
typedef __attribute__((ext_vector_type(8))) int   int8v;
typedef __attribute__((ext_vector_type(4))) float f32x4;

#define AS1 __attribute__((address_space(1)))
#define AS3 __attribute__((address_space(3)))

// ---------------------------------------------------------------------------
// prep: grid-stride, one wave per row per iter. fp32 -> fp8 e4m3 (OCP) +
// exact fp32 ||row||^2. Also zeroes rowsum[M].
// ---------------------------------------------------------------------------
__global__ __launch_bounds__(256) void prep_kernel(
    const float* __restrict__ X, const float* __restrict__ S,
    unsigned char* __restrict__ Xq, unsigned char* __restrict__ Sq,
    float* __restrict__ x2, float* __restrict__ s2,
    float* __restrict__ rowsum, int M, int R, int Dv)
{
    const int gid  = blockIdx.x * 256 + threadIdx.x;
    const int nthr = gridDim.x * 256;

    for (int i = gid; i < M; i += nthr) rowsum[i] = 0.f;

    const int lane = threadIdx.x & 63;
    const int wid  = gid >> 6;
    const int nw   = nthr >> 6;

    for (int row = wid; row < R; row += nw) {
        const float* rp;
        unsigned char* op;
        float* sq;
        if (row < M) { rp = X + (size_t)row * Dv;       op = Xq + (size_t)row * Dv;       sq = x2 + row; }
        else         { rp = S + (size_t)(row - M) * Dv; op = Sq + (size_t)(row - M) * Dv; sq = s2 + (row - M); }

        float acc = 0.f;
        for (int k = lane * 8; k < Dv; k += 64 * 8) {
            float4 v0 = *(const float4*)(rp + k);
            float4 v1 = *(const float4*)(rp + k + 4);
            acc += v0.x * v0.x + v0.y * v0.y + v0.z * v0.z + v0.w * v0.w;
            acc += v1.x * v1.x + v1.y * v1.y + v1.z * v1.z + v1.w * v1.w;
            union { __hip_fp8_e4m3 h[8]; uint2 u; } pk;
            pk.h[0] = __hip_fp8_e4m3(v0.x);
            pk.h[1] = __hip_fp8_e4m3(v0.y);
            pk.h[2] = __hip_fp8_e4m3(v0.z);
            pk.h[3] = __hip_fp8_e4m3(v0.w);
            pk.h[4] = __hip_fp8_e4m3(v1.x);
            pk.h[5] = __hip_fp8_e4m3(v1.y);
            pk.h[6] = __hip_fp8_e4m3(v1.z);
            pk.h[7] = __hip_fp8_e4m3(v1.w);
            *(uint2*)(op + k) = pk.u;
        }
#pragma unroll
        for (int off = 1; off < 64; off <<= 1)
            acc += __shfl_xor(acc, off, 64);
        if (lane == 0) *sq = acc;
    }
}

// ---------------------------------------------------------------------------
// D=512 fused fp8 GEMM + exp-reduce. R4 2-barrier skeleton, widened:
// 512 threads = 8 waves (4m x 2n grid of 64x64 quadrants), tile 256x128,
// BK=128, single 48 KB buffer (A 32 KB + B 16 KB), 4 K-iters.
// NOTE: __launch_bounds__(512) with NO min-waves arg — R8's (512,4) capped
// the allocator at 64 VGPRs and spilled acc[][] to scratch (WRITE_SIZE
// 4 KB -> 135 MB). The allocator must be free to take ~130-180 regs.
// LDS 16-B-chunk XOR swizzle phys = c ^ (row&7) (R2/R4-verified).
// ---------------------------------------------------------------------------
__global__ __launch_bounds__(512) void kde_gemm512(
    const unsigned char* __restrict__ Xq,   // [M][512] fp8 e4m3
    const unsigned char* __restrict__ Sq,   // [N][512] fp8 e4m3
    const float* __restrict__ x2,
    const float* __restrict__ s2,
    const float* __restrict__ scale_p,
    float* __restrict__ rowsum,
    int M, int N)
{
    __shared__ char smem[49152];   // As [256][128] 32 KB | Bs [128][128] 16 KB
    unsigned char* As = (unsigned char*)smem;
    unsigned char* Bs = (unsigned char*)(smem + 32768);

    const int tid  = threadIdx.x;
    const int wave = tid >> 6;
    const int lane = tid & 63;
    const int quad = lane >> 4;
    const int l16  = lane & 15;

    const int m0 = blockIdx.x * 256;
    const int n0 = blockIdx.y * 128;
    const int wm = (wave >> 1) * 64;   // 4 m-strips
    const int wn = (wave & 1) * 64;    // 2 n-strips

    const float sc = *scale_p;

    f32x4 acc[4][4] = {};

    // staging map: a round covers 64 rows x 128 B = 8 KB (512 thr x 16 B).
    // thread t: row-in-round = t>>3, phys chunk = t&7,
    // global chunk = (t&7) ^ (row&7) = (t&7) ^ ((t>>3)&7).
    // LDS dst = round_base + t*16  (wave-uniform base + lane*16  ✓).
    const int srow = tid >> 3;                     // 0..63
    const int cg   = (tid & 7) ^ (srow & 7);
    const unsigned char* gA = Xq + (size_t)(m0 + srow) * 512 + cg * 16;
    const unsigned char* gB = Sq + (size_t)(n0 + srow) * 512 + cg * 16;

#pragma unroll
    for (int k0 = 0; k0 < 512; k0 += 128) {
        __syncthreads();  // prev iter's ds_reads done before overwrite
#pragma unroll
        for (int rd = 0; rd < 4; ++rd)   // A: 4 rounds of 64 rows
            __builtin_amdgcn_global_load_lds(
                (const AS1 void*)(gA + (size_t)rd * 64 * 512 + k0),
                (AS3 void*)(smem + rd * 8192 + wave * 1024), 16, 0, 0);
#pragma unroll
        for (int rd = 0; rd < 2; ++rd)   // B: 2 rounds of 64 rows
            __builtin_amdgcn_global_load_lds(
                (const AS1 void*)(gB + (size_t)rd * 64 * 512 + k0),
                (AS3 void*)(smem + 32768 + rd * 8192 + wave * 1024), 16, 0, 0);
        __syncthreads();  // staging drained

        const int e = l16 & 7;
        int8v a_frag[4], b_frag[4];
#pragma unroll
        for (int mi = 0; mi < 4; ++mi) {
            const unsigned char* rowp = As + (size_t)(wm + mi * 16 + l16) * 128;
            int4v lo = *(const int4v*)(rowp + ((2 * quad)     ^ e) * 16);
            int4v hi = *(const int4v*)(rowp + ((2 * quad + 1) ^ e) * 16);
            a_frag[mi] = (int8v){lo.x, lo.y, lo.z, lo.w, hi.x, hi.y, hi.z, hi.w};
        }
#pragma unroll
        for (int ni = 0; ni < 4; ++ni) {
            const unsigned char* rowp = Bs + (size_t)(wn + ni * 16 + l16) * 128;
            int4v lo = *(const int4v*)(rowp + ((2 * quad)     ^ e) * 16);
            int4v hi = *(const int4v*)(rowp + ((2 * quad + 1) ^ e) * 16);
            b_frag[ni] = (int8v){lo.x, lo.y, lo.z, lo.w, hi.x, hi.y, hi.z, hi.w};
        }
#pragma unroll
        for (int mi = 0; mi < 4; ++mi)
#pragma unroll
            for (int ni = 0; ni < 4; ++ni)
                acc[mi][ni] = __builtin_amdgcn_mfma_scale_f32_16x16x128_f8f6f4(
                    a_frag[mi], b_frag[ni], acc[mi][ni],
                    0, 0, 0, 0x7F7F7F7F, 0, 0x7F7F7F7F);
    }

    // ---- epilogue. C layout: col = l16 (-> n), row = quad*4 + reg (-> m).
    __syncthreads();  // all waves done reading As/Bs; reuse LDS
    float* wred = (float*)(smem + wave * 5120);   // 8 x 5120 B = 40 KB

    float s2v[4];
#pragma unroll
    for (int ni = 0; ni < 4; ++ni)
        s2v[ni] = s2[n0 + wn + ni * 16 + l16];

#pragma unroll
    for (int mi = 0; mi < 4; ++mi) {
#pragma unroll
        for (int r = 0; r < 4; ++r) {
            const int rowL = mi * 16 + quad * 4 + r;   // 0..63 within wave
            const float xv = x2[m0 + wm + rowL];
            float sum = 0.f;
#pragma unroll
            for (int ni = 0; ni < 4; ++ni) {
                float d2 = xv + s2v[ni] - 2.0f * acc[mi][ni][r];
                d2 = fmaxf(d2, 0.f);
                sum += __expf(-sc * d2);
            }
            wred[rowL * 20 + l16] = sum;
        }
    }
    __syncthreads();

    float* rp = wred + lane * 20;
    float4 p0 = *(float4*)(rp + 0);
    float4 p1 = *(float4*)(rp + 4);
    float4 p2 = *(float4*)(rp + 8);
    float4 p3 = *(float4*)(rp + 12);
    float s = (p0.x + p0.y + p0.z + p0.w) + (p1.x + p1.y + p1.z + p1.w)
            + (p2.x + p2.y + p2.z + p2.w) + (p3.x + p3.y + p3.z + p3.w);
    atomicAdd(&rowsum[m0 + wm + lane], s);
}

// ---------------------------------------------------------------------------
// Generic-D fallback (R4 structure, verified): 2-barrier K-loop, BK=128.
// ---------------------------------------------------------------------------
__global__ __launch_bounds__(256, 3) void kde_gemm_generic(
    const unsigned char* __restrict__ Xq, const unsigned char* __restrict__ Sq,
    const float* __restrict__ x2, const float* __restrict__ s2,
    const float* __restrict__ scale_p, float* __restrict__ rowsum,
    int M, int N, int Dv)
{
    const int D = Dv;
    __shared__ char smem[32768];
    unsigned char* As = (unsigned char*)smem;
    unsigned char* Bs = (unsigned char*)(smem + 16384);

    const int tid  = threadIdx.x;
    const int wave = tid >> 6;
    const int lane = tid & 63;
    const int quad = lane >> 4;
    const int l16  = lane & 15;

    const int m0 = blockIdx.x * 128;
    const int n0 = blockIdx.y * 128;
    const int wm = (wave & 1) * 64;
    const int wn = (wave >> 1) * 64;

    const float sc = *scale_p;
    f32x4 acc[4][4] = {};

    const int srow0 = wave * 8 + (lane >> 3);
    const int cg    = (lane & 7) ^ (lane >> 3);
    const unsigned char* gA = Xq + (size_t)(m0 + srow0) * D + cg * 16;
    const unsigned char* gB = Sq + (size_t)(n0 + srow0) * D + cg * 16;

    for (int k0 = 0; k0 < D; k0 += 128) {
        __syncthreads();
#pragma unroll
        for (int rd = 0; rd < 4; ++rd)
            __builtin_amdgcn_global_load_lds(
                (const AS1 void*)(gA + (size_t)rd * 32 * D + k0),
                (AS3 void*)(smem + rd * 4096 + wave * 1024), 16, 0, 0);
#pragma unroll
        for (int rd = 0; rd < 4; ++rd)
            __builtin_amdgcn_global_load_lds(
                (const AS1 void*)(gB + (size_t)rd * 32 * D + k0),
                (AS3 void*)(smem + 16384 + rd * 4096 + wave * 1024), 16, 0, 0);
        __syncthreads();

        const int e = l16 & 7;
        int8v a_frag[4], b_frag[4];
#pragma unroll
        for (int mi = 0; mi < 4; ++mi) {
            const unsigned char* rowp = As + (wm + mi * 16 + l16) * 128;
            int4v lo = *(const int4v*)(rowp + ((2 * quad)     ^ e) * 16);
            int4v hi = *(const int4v*)(rowp + ((2 * quad + 1) ^ e) * 16);
            a_frag[mi] = (int8v){lo.x, lo.y, lo.z, lo.w, hi.x, hi.y, hi.z, hi.w};
        }
#pragma unroll
        for (int ni = 0; ni < 4; ++ni) {
            const unsigned char* rowp = Bs + (wn + ni * 16 + l16) * 128;
            int4v lo = *(const int4v*)(rowp + ((2 * quad)     ^ e) * 16);
            int4v hi = *(const int4v*)(rowp + ((2 * quad + 1) ^ e) * 16);
            b_frag[ni] = (int8v){lo.x, lo.y, lo.z, lo.w, hi.x, hi.y, hi.z, hi.w};
        }
#pragma unroll
        for (int mi = 0; mi < 4; ++mi)
#pragma unroll
            for (int ni = 0; ni < 4; ++ni)
                acc[mi][ni] = __builtin_amdgcn_mfma_scale_f32_16x16x128_f8f6f4(
                    a_frag[mi], b_frag[ni], acc[mi][ni],
                    0, 0, 0, 0x7F7F7F7F, 0, 0x7F7F7F7F);
    }

    __syncthreads();
    float* wred = (float*)smem + wave * (64 * 20);

    float s2v[4];
#pragma unroll
    for (int ni = 0; ni < 4; ++ni)
        s2v[ni] = s2[n0 + wn + ni * 16 + l16];

#pragma unroll
    for (int mi = 0; mi < 4; ++mi) {
#pragma unroll
        for (int r = 0; r < 4; ++r) {
            const int rowL = mi * 16 + quad * 4 + r;
            const float xv = x2[m0 + wm + rowL];
            float sum = 0.f;
#pragma unroll
            for (int ni = 0; ni < 4; ++ni) {
                float d2 = xv + s2v[ni] - 2.0f * acc[mi][ni][r];
                d2 = fmaxf(d2, 0.f);
                sum += __expf(-sc * d2);
            }
            wred[rowL * 20 + l16] = sum;
        }
    }
    __syncthreads();

    float4 p0 = *(float4*)(wred + lane * 20 + 0);
    float4 p1 = *(float4*)(wred + lane * 20 + 4);
    float4 p2 = *(float4*)(wred + lane * 20 + 8);
    float4 p3 = *(float4*)(wred + lane * 20 + 12);
    float s = (p0.x + p0.y + p0.z + p0.w) + (p1.x + p1.y + p1.z + p1.w)
            + (p2.x + p2.y + p2.z + p2.w) + (p3.x + p3.y + p3.z + p3.w);
    atomicAdd(&rowsum[m0 + wm + lane], s);
}

// ---------------------------------------------------------------------------
__global__ void finalize_kernel(const float* __restrict__ rowsum,
                                const float* __restrict__ scale_p,
                                float* __restrict__ out, int M, int N, int Dv) {
    const int m = blockIdx.x * 256 + threadIdx.x;
    if (m < M) {
        const float sc = *scale_p;
        const float cst = -logf((float)N) + 0.5f * (float)Dv * logf(sc / 3.14159265358979f);
        out[m] = logf(rowsum[m]) + cst;
    }
}

// ---------------------------------------------------------------------------
extern "C" void kernel_launch(void* const* d_in, const int* in_sizes, int n_in,
                              void* d_out, int out_size, void* d_ws, size_t ws_size,
                              hipStream_t stream) {
    const float* X       = (const float*)d_in[0];
    const float* S       = (const float*)d_in[1];
    const float* scale_p = (const float*)d_in[2];
    float* out = (float*)d_out;

    const int M  = out_size;            // 8192
    const int Dv = in_sizes[0] / M;     // 512
    const int N  = in_sizes[1] / Dv;    // 8192

    char* ws = (char*)d_ws;
    unsigned char* Xq = (unsigned char*)ws;
    unsigned char* Sq = (unsigned char*)(ws + (size_t)M * Dv);
    float* x2     = (float*)(ws + (size_t)M * Dv + (size_t)N * Dv);
    float* s2     = x2 + M;
    float* rowsum = s2 + N;

    prep_kernel<<<512, 256, 0, stream>>>(X, S, Xq, Sq, x2, s2, rowsum, M, M + N, Dv);

    if (Dv == 512 && (M % 256) == 0 && (N % 128) == 0) {
        dim3 grid(M / 256, N / 128);
        kde_gemm512<<<grid, 512, 0, stream>>>(Xq, Sq, x2, s2, scale_p, rowsum, M, N);
    } else {
        dim3 grid(M / 128, N / 128);
        kde_gemm_generic<<<grid, 256, 0, stream>>>(Xq, Sq, x2, s2, scale_p, rowsum, M, N, Dv);
    }

    finalize_kernel<<<(M + 255) / 256, 256, 0, stream>>>(rowsum, scale_p, out, M, N, Dv);
}